// Round 4
// baseline (545.257 us; speedup 1.0000x reference)
//
#include <hip/hip_runtime.h>
#include <hip/hip_bf16.h>

// LSTM_single_task: B=32768, I=H=512. Inputs/outputs CONFIRMED fp32 (R3).
// Live math: 3 gate GEMMs (i,c,o) over u=[x,h] (K=1024), fused activations;
// f-gate and c_prev dead.
//
// R4: (a) prepass converts x,h -> bf16 U[32768][1024] in d_ws (fp32 staging
// cost + cvt VALU leaves the K-loop); (b) m97-style async global_load_lds
// width=16 staging; (c) XOR bank swizzle on LDS k-chunks (key=(row>>1)&3)
// so 16-lane frag reads hit all 8 bank-groups (2-way = free) instead of 2
// (8-way). Host guard: if ws_size < 68MB, fall back to R3-proven kernel.

typedef unsigned short u16;
typedef __bf16 bf16x8 __attribute__((ext_vector_type(8)));
typedef float f32x4 __attribute__((ext_vector_type(4)));

#define B_DIM 32768
#define K_DIM 1024
#define BH_ELEMS (B_DIM * 512)   // 16,777,216

__device__ __forceinline__ void async_load16(const void* g, void* l) {
    __builtin_amdgcn_global_load_lds(
        (const __attribute__((address_space(1))) void*)g,
        (__attribute__((address_space(3))) void*)l, 16, 0, 0);
}

__device__ __forceinline__ u16 f2bf16u(float f) {
    __hip_bfloat16 b = __float2bfloat16(f);   // RNE
    u16 u;
    __builtin_memcpy(&u, &b, 2);
    return u;
}

__device__ __forceinline__ float fast_sigmoid(float x) {
    return 1.0f / (1.0f + __expf(-x));
}

__device__ __forceinline__ float fast_tanh(float x) {
    float e = __expf(-2.0f * fabsf(x));     // in (0,1], never overflows
    float r = (1.0f - e) / (1.0f + e);
    return x < 0.0f ? -r : r;
}

// -------- prepass: U[row][0:512]=bf16(x[row]), [512:1024]=bf16(h[row]) ----
// grid 8192 x 256; one 8-elem chunk of x and of h per thread.
__global__ void convert_u(const float* __restrict__ x, const float* __restrict__ h,
                          __bf16* __restrict__ U)
{
    const int c = blockIdx.x * 256 + threadIdx.x;   // [0, 32768*64)
    const int row = c >> 6, cc = c & 63;
    const float* xs = x + (long)row * 512 + cc * 8;
    const float* hs = h + (long)row * 512 + cc * 8;
    f32x4 a0 = *(const f32x4*)xs, a1 = *(const f32x4*)(xs + 4);
    f32x4 b0 = *(const f32x4*)hs, b1 = *(const f32x4*)(hs + 4);
    bf16x8 va, vb;
#pragma unroll
    for (int j = 0; j < 4; ++j) {
        va[j] = (__bf16)a0[j]; va[4 + j] = (__bf16)a1[j];
        vb[j] = (__bf16)b0[j]; vb[4 + j] = (__bf16)b1[j];
    }
    *(bf16x8*)(U + (long)row * 1024 + cc * 8)       = va;
    *(bf16x8*)(U + (long)row * 1024 + 512 + cc * 8) = vb;
}

// -------- prep: pack W into Wt[g][n][k] (bf16), n-major, k = [Wx ; Wh] -----
__global__ void pack_weights(const float* __restrict__ Wxi, const float* __restrict__ Whi,
                             const float* __restrict__ Wxc, const float* __restrict__ Whc,
                             const float* __restrict__ Wxo, const float* __restrict__ Who,
                             u16* __restrict__ Wt)
{
    __shared__ u16 tile[32][33];
    const int g = blockIdx.z >> 1, half = blockIdx.z & 1;
    const float* src;
    if (g == 0)      src = half ? Whi : Wxi;
    else if (g == 1) src = half ? Whc : Wxc;
    else             src = half ? Who : Wxo;
    const int kk = blockIdx.y * 32, nn = blockIdx.x * 32;
    const int tx = threadIdx.x, ty = threadIdx.y;
#pragma unroll
    for (int i2 = 0; i2 < 4; ++i2)
        tile[ty + 8 * i2][tx] = f2bf16u(src[(kk + ty + 8 * i2) * 512 + nn + tx]);
    __syncthreads();
#pragma unroll
    for (int i2 = 0; i2 < 4; ++i2)
        Wt[(long)g * 524288 + (long)(nn + ty + 8 * i2) * 1024 + half * 512 + kk + tx]
            = tile[tx][ty + 8 * i2];
}

// -------- FAST main: async-staged bf16 GEMM, swizzled LDS -----------------
// grid (8, 256): n0 = 64*bx, m0 = 128*by. 256 threads, 4 waves (2m x 2n).
// LDS chunk layout: As chunk = row*4 + (kc ^ ((row>>1)&3)); same for Bs/gate.
__global__ __launch_bounds__(256) void lstm_gemm_fast(
    const u16* __restrict__ U, const u16* __restrict__ Wt,
    const float* __restrict__ bxi, const float* __restrict__ bxc,
    const float* __restrict__ bxo, float* __restrict__ out)
{
    __shared__ __align__(16) u16 As[128 * 32];       // 8 KB
    __shared__ __align__(16) u16 Bs[3 * 64 * 32];    // 12 KB

    const int tid    = threadIdx.x;
    const int lane   = tid & 63;
    const int wave   = tid >> 6;
    const int wave_m = wave & 1;
    const int wave_n = wave >> 1;
    const int m0 = blockIdx.y * 128;
    const int n0 = blockIdx.x * 64;

    // ---- staging: lane handles chunk (64*wave + lane) of each region -------
    // chunk c -> row = c>>2, kc_lds = c&3, global kc = kc_lds ^ ((row>>1)&3)
    const int arow = tid >> 2;                       // 0..63
    const int kcl  = tid & 3;
    const int kcg  = kcl ^ ((arow >> 1) & 3);
    const long aoff0 = (long)(m0 + arow) * 1024 + kcg * 8;        // rows 0..63
    const long aoff1 = aoff0 + (long)64 * 1024;                   // rows 64..127 (same key)
    long boff[3];
#pragma unroll
    for (int j = 0; j < 3; ++j)
        boff[j] = (long)j * 524288 + (long)(n0 + arow) * 1024 + kcg * 8;

    u16* const aldst0 = &As[wave * 512];
    u16* const aldst1 = &As[2048 + wave * 512];
    u16* bldst[3];
#pragma unroll
    for (int j = 0; j < 3; ++j)
        bldst[j] = &Bs[j * 2048 + wave * 512];

    // ---- fragment LDS offsets (swizzled) -----------------------------------
    const int r15 = lane & 15, kc = lane >> 4;
    const int key = kc ^ ((r15 >> 1) & 3);           // row base mult of 16 -> key row-invariant
    int a_ld[4];
#pragma unroll
    for (int mt = 0; mt < 4; ++mt)
        a_ld[mt] = ((wave_m * 64 + mt * 16 + r15) * 4 + key) * 8;
    int b_ld[3][2];
#pragma unroll
    for (int g = 0; g < 3; ++g)
#pragma unroll
        for (int nt = 0; nt < 2; ++nt)
            b_ld[g][nt] = g * 2048 + ((wave_n * 32 + nt * 16 + r15) * 4 + key) * 8;

    f32x4 acc[3][4][2];
    const f32x4 zero = {0.f, 0.f, 0.f, 0.f};
#pragma unroll
    for (int g = 0; g < 3; ++g)
#pragma unroll
        for (int mt = 0; mt < 4; ++mt)
#pragma unroll
            for (int nt = 0; nt < 2; ++nt)
                acc[g][mt][nt] = zero;

    for (int k0 = 0; k0 < K_DIM; k0 += 32) {
        __syncthreads();   // prior iter's ds_reads done -> safe to overwrite
        async_load16(U + aoff0 + k0, aldst0);
        async_load16(U + aoff1 + k0, aldst1);
#pragma unroll
        for (int j = 0; j < 3; ++j)
            async_load16(Wt + boff[j] + k0, bldst[j]);
        __syncthreads();   // compiler drains vmcnt before s_barrier (m97)

        bf16x8 af[4];
#pragma unroll
        for (int mt = 0; mt < 4; ++mt)
            af[mt] = *(const bf16x8*)&As[a_ld[mt]];
        bf16x8 bfr[3][2];
#pragma unroll
        for (int g = 0; g < 3; ++g)
#pragma unroll
            for (int nt = 0; nt < 2; ++nt)
                bfr[g][nt] = *(const bf16x8*)&Bs[b_ld[g][nt]];

#pragma unroll
        for (int g = 0; g < 3; ++g)
#pragma unroll
            for (int mt = 0; mt < 4; ++mt)
#pragma unroll
            for (int nt = 0; nt < 2; ++nt)
                acc[g][mt][nt] = __builtin_amdgcn_mfma_f32_16x16x32_bf16(
                    af[mt], bfr[g][nt], acc[g][mt][nt], 0, 0, 0);
    }

    // ---- epilogue (verified R3): col = lane&15 (+16nt), row = (lane>>4)*4+r -
    const int colbase = n0 + wave_n * 32 + r15;
    float bi[2], bc[2], bo[2];
#pragma unroll
    for (int nt = 0; nt < 2; ++nt) {
        const int col = colbase + nt * 16;
        bi[nt] = bxi[col]; bc[nt] = bxc[col]; bo[nt] = bxo[col];
    }
    const int rowbase = m0 + wave_m * 64 + kc * 4;
#pragma unroll
    for (int mt = 0; mt < 4; ++mt)
#pragma unroll
        for (int nt = 0; nt < 2; ++nt)
#pragma unroll
            for (int r = 0; r < 4; ++r) {
                const int row = rowbase + mt * 16 + r;
                const int col = colbase + nt * 16;
                const float iv = fast_sigmoid(acc[0][mt][nt][r] + bi[nt]);
                const float cv = iv * fast_tanh(acc[1][mt][nt][r] + bc[nt]);
                const float ov = fast_sigmoid(acc[2][mt][nt][r] + bo[nt]);
                const float hv = ov * fast_tanh(cv);
                const long idx = (long)row * 512 + col;
                out[idx]            = hv;
                out[BH_ELEMS + idx] = cv;
            }
}

// -------- FALLBACK main (R3-proven, fp32-direct) if ws too small ----------
typedef u16 u16x8 __attribute__((ext_vector_type(8)));
__global__ __launch_bounds__(256, 2) void lstm_gemm_fb(
    const float* __restrict__ x, const float* __restrict__ h,
    const u16* __restrict__ Wt,
    const float* __restrict__ bxi, const float* __restrict__ bxc,
    const float* __restrict__ bxo, float* __restrict__ out)
{
    __shared__ __align__(16) u16 As[128 * 32];
    __shared__ __align__(16) u16 Bs[3 * 64 * 32];
    const int tid = threadIdx.x, lane = tid & 63, wave = tid >> 6;
    const int wave_m = wave & 1, wave_n = wave >> 1;
    const int m0 = blockIdx.y * 128, n0 = blockIdx.x * 64;
    const int trow = tid >> 2, tkc = (tid & 3) * 8;
    const long a_g0 = (long)(m0 + trow) * 512 + tkc;
    const long a_g1 = (long)(m0 + 64 + trow) * 512 + tkc;
    long b_g[3];
#pragma unroll
    for (int q = 0; q < 3; ++q)
        b_g[q] = (long)q * 524288 + (long)(n0 + trow) * 1024 + tkc;
    int a_ld[4];
#pragma unroll
    for (int mt = 0; mt < 4; ++mt)
        a_ld[mt] = (wave_m * 64 + mt * 16 + (lane & 15)) * 32 + (lane >> 4) * 8;
    int b_ld[3][2];
#pragma unroll
    for (int g = 0; g < 3; ++g)
#pragma unroll
        for (int nt = 0; nt < 2; ++nt)
            b_ld[g][nt] = g * 2048 + (wave_n * 32 + nt * 16 + (lane & 15)) * 32 + (lane >> 4) * 8;
    f32x4 acc[3][4][2];
    const f32x4 zero = {0.f, 0.f, 0.f, 0.f};
#pragma unroll
    for (int g = 0; g < 3; ++g)
#pragma unroll
        for (int mt = 0; mt < 4; ++mt)
#pragma unroll
            for (int nt = 0; nt < 2; ++nt) acc[g][mt][nt] = zero;
    for (int k0 = 0; k0 < K_DIM; k0 += 32) {
        const float* s = ((k0 < 512) ? x : h) + ((k0 < 512) ? k0 : (k0 - 512));
        bf16x8 av0, av1, bv[3];
        f32x4 p0 = *(const f32x4*)(s + a_g0), p1 = *(const f32x4*)(s + a_g0 + 4);
        f32x4 q0 = *(const f32x4*)(s + a_g1), q1 = *(const f32x4*)(s + a_g1 + 4);
#pragma unroll
        for (int j = 0; j < 4; ++j) {
            av0[j] = (__bf16)p0[j]; av0[4 + j] = (__bf16)p1[j];
            av1[j] = (__bf16)q0[j]; av1[4 + j] = (__bf16)q1[j];
        }
#pragma unroll
        for (int q = 0; q < 3; ++q) {
            u16x8 t = *(const u16x8*)(Wt + b_g[q] + k0);
            __builtin_memcpy(&bv[q], &t, 16);
        }
        __syncthreads();
        *(bf16x8*)&As[tid * 8] = av0;
        *(bf16x8*)&As[2048 + tid * 8] = av1;
#pragma unroll
        for (int q = 0; q < 3; ++q) *(bf16x8*)&Bs[q * 2048 + tid * 8] = bv[q];
        __syncthreads();
        bf16x8 af[4];
#pragma unroll
        for (int mt = 0; mt < 4; ++mt) af[mt] = *(const bf16x8*)&As[a_ld[mt]];
        bf16x8 bfr[3][2];
#pragma unroll
        for (int g = 0; g < 3; ++g)
#pragma unroll
            for (int nt = 0; nt < 2; ++nt) bfr[g][nt] = *(const bf16x8*)&Bs[b_ld[g][nt]];
#pragma unroll
        for (int g = 0; g < 3; ++g)
#pragma unroll
            for (int mt = 0; mt < 4; ++mt)
#pragma unroll
            for (int nt = 0; nt < 2; ++nt)
                acc[g][mt][nt] = __builtin_amdgcn_mfma_f32_16x16x32_bf16(
                    af[mt], bfr[g][nt], acc[g][mt][nt], 0, 0, 0);
    }
    const int colbase = n0 + wave_n * 32 + (lane & 15);
    float bi[2], bc[2], bo[2];
#pragma unroll
    for (int nt = 0; nt < 2; ++nt) {
        const int col = colbase + nt * 16;
        bi[nt] = bxi[col]; bc[nt] = bxc[col]; bo[nt] = bxo[col];
    }
    const int rowbase = m0 + wave_m * 64 + (lane >> 4) * 4;
#pragma unroll
    for (int mt = 0; mt < 4; ++mt)
#pragma unroll
        for (int nt = 0; nt < 2; ++nt)
#pragma unroll
            for (int r = 0; r < 4; ++r) {
                const int row = rowbase + mt * 16 + r;
                const int col = colbase + nt * 16;
                const float iv = fast_sigmoid(acc[0][mt][nt][r] + bi[nt]);
                const float cv = iv * fast_tanh(acc[1][mt][nt][r] + bc[nt]);
                const float ov = fast_sigmoid(acc[2][mt][nt][r] + bo[nt]);
                const float hv = ov * fast_tanh(cv);
                const long idx = (long)row * 512 + col;
                out[idx] = hv;
                out[BH_ELEMS + idx] = cv;
            }
}

extern "C" void kernel_launch(void* const* d_in, const int* in_sizes, int n_in,
                              void* d_out, int out_size, void* d_ws, size_t ws_size,
                              hipStream_t stream) {
    const float* x   = (const float*)d_in[0];
    const float* h   = (const float*)d_in[1];
    const float* Wxi = (const float*)d_in[3];
    const float* bxi = (const float*)d_in[4];
    const float* Whi = (const float*)d_in[5];
    const float* Wxc = (const float*)d_in[9];
    const float* bxc = (const float*)d_in[10];
    const float* Whc = (const float*)d_in[11];
    const float* Wxo = (const float*)d_in[12];
    const float* bxo = (const float*)d_in[13];
    const float* Who = (const float*)d_in[14];
    float* out = (float*)d_out;

    const size_t U_BYTES = (size_t)B_DIM * K_DIM * 2;        // 64 MB
    const size_t WT_BYTES = (size_t)3 * 512 * 1024 * 2;      // 3 MB

    if (ws_size >= U_BYTES + WT_BYTES) {
        __bf16* U = (__bf16*)d_ws;
        u16* Wt = (u16*)((char*)d_ws + U_BYTES);
        convert_u<<<8192, 256, 0, stream>>>(x, h, U);
        pack_weights<<<dim3(16, 16, 6), dim3(32, 8), 0, stream>>>(
            Wxi, Whi, Wxc, Whc, Wxo, Who, Wt);
        lstm_gemm_fast<<<dim3(8, 256), dim3(256), 0, stream>>>(
            (const u16*)U, Wt, bxi, bxc, bxo, out);
    } else {
        u16* Wt = (u16*)d_ws;
        pack_weights<<<dim3(16, 16, 6), dim3(32, 8), 0, stream>>>(
            Wxi, Whi, Wxc, Whc, Wxo, Who, Wt);
        lstm_gemm_fb<<<dim3(8, 256), dim3(256), 0, stream>>>(
            x, h, Wt, bxi, bxc, bxo, out);
    }
}